// Round 1
// baseline (1247.126 us; speedup 1.0000x reference)
//
#include <hip/hip_runtime.h>
#include <cstddef>

#define HEADS 4
#define HC 128          // HEADS * C
#define SLOPE 0.2f

// ---------------------------------------------------------------------------
// K1: init softmax denominators to epsilon and out to bias broadcast
// ---------------------------------------------------------------------------
__global__ void init_kernel(float* __restrict__ s, float* __restrict__ out,
                            const float* __restrict__ bias, int n) {
    int i = blockIdx.x * blockDim.x + threadIdx.x;
    int total = n * HC;
    if (i < total) out[i] = bias[i & (HC - 1)];
    if (i < n * HEADS) s[i] = 1e-16f;
}

// ---------------------------------------------------------------------------
// K2: h = x @ W   (N x 128) @ (128 x 128), fp32 vector GEMM
// Block: 256 threads, 128 rows x 128 cols per block, 8x8 per thread.
// K chunked by 32 so static LDS stays under 64 KB (W chunk 16KB + xT 16.9KB).
// ---------------------------------------------------------------------------
__global__ __launch_bounds__(256)
void gemm_kernel(const float* __restrict__ x, const float* __restrict__ W,
                 float* __restrict__ h, int n) {
    __shared__ float Wl[32 * 128];   // [kl][c]
    __shared__ float xT[32 * 132];   // [kl][r], padded stride 132 (16B-aligned rows)

    const int tid  = threadIdx.x;
    const int row0 = blockIdx.x * 128;
    const int r0   = (tid >> 4) * 8;   // 16 row-groups of 8
    const int c0   = (tid & 15) * 8;   // 16 col-groups of 8

    float acc[8][8];
#pragma unroll
    for (int i = 0; i < 8; ++i)
#pragma unroll
        for (int j = 0; j < 8; ++j) acc[i][j] = 0.f;

    const float4* x4 = (const float4*)x;
    const float4* W4 = (const float4*)W;

    for (int kc = 0; kc < 4; ++kc) {
        // stage W chunk: k rows kc*32..+32, all 128 cols = 1024 float4
        for (int i = tid; i < 1024; i += 256)
            ((float4*)Wl)[i] = W4[kc * 1024 + i];
        // stage x chunk transposed: 128 rows x 32 k = 1024 float4
        for (int i = tid; i < 1024; i += 256) {
            int r = i >> 3;        // 0..127 tile row
            int q = i & 7;         // float4 index within the 32-k chunk
            int grow = row0 + r;
            float4 v = make_float4(0.f, 0.f, 0.f, 0.f);
            if (grow < n) v = x4[(size_t)grow * 32 + kc * 8 + q];
            int kl = q * 4;
            xT[(kl + 0) * 132 + r] = v.x;
            xT[(kl + 1) * 132 + r] = v.y;
            xT[(kl + 2) * 132 + r] = v.z;
            xT[(kl + 3) * 132 + r] = v.w;
        }
        __syncthreads();
#pragma unroll
        for (int kl = 0; kl < 32; ++kl) {
            float4 xa = *(const float4*)&xT[kl * 132 + r0];
            float4 xb = *(const float4*)&xT[kl * 132 + r0 + 4];
            float4 wa = *(const float4*)&Wl[kl * 128 + c0];
            float4 wb = *(const float4*)&Wl[kl * 128 + c0 + 4];
            float xr[8] = {xa.x, xa.y, xa.z, xa.w, xb.x, xb.y, xb.z, xb.w};
            float wc[8] = {wa.x, wa.y, wa.z, wa.w, wb.x, wb.y, wb.z, wb.w};
#pragma unroll
            for (int i = 0; i < 8; ++i)
#pragma unroll
                for (int j = 0; j < 8; ++j)
                    acc[i][j] = fmaf(xr[i], wc[j], acc[i][j]);
        }
        __syncthreads();
    }

#pragma unroll
    for (int i = 0; i < 8; ++i) {
        int grow = row0 + r0 + i;
        if (grow < n) {
            float4 o0 = make_float4(acc[i][0], acc[i][1], acc[i][2], acc[i][3]);
            float4 o1 = make_float4(acc[i][4], acc[i][5], acc[i][6], acc[i][7]);
            *(float4*)&h[(size_t)grow * HC + c0]     = o0;
            *(float4*)&h[(size_t)grow * HC + c0 + 4] = o1;
        }
    }
}

// ---------------------------------------------------------------------------
// K3: per-node attention logit halves: a_src[n,h] = <h[n,h,:], att_src[h,:]>
// ---------------------------------------------------------------------------
__global__ void att_kernel(const float* __restrict__ h,
                           const float* __restrict__ att_src,
                           const float* __restrict__ att_dst,
                           float* __restrict__ a_s, float* __restrict__ a_d, int n) {
    int node = blockIdx.x * blockDim.x + threadIdx.x;
    if (node >= n) return;
    const float4* hv = (const float4*)(h + (size_t)node * HC);
    const float4* s4 = (const float4*)att_src;
    const float4* d4 = (const float4*)att_dst;
    float rs[4], rd[4];
#pragma unroll
    for (int hd = 0; hd < 4; ++hd) {
        float ss = 0.f, dd = 0.f;
#pragma unroll
        for (int q = 0; q < 8; ++q) {
            float4 hq = hv[hd * 8 + q];
            float4 a1 = s4[hd * 8 + q];
            float4 a2 = d4[hd * 8 + q];
            ss += hq.x * a1.x + hq.y * a1.y + hq.z * a1.z + hq.w * a1.w;
            dd += hq.x * a2.x + hq.y * a2.y + hq.z * a2.z + hq.w * a2.w;
        }
        rs[hd] = ss; rd[hd] = dd;
    }
    ((float4*)a_s)[node] = make_float4(rs[0], rs[1], rs[2], rs[3]);
    ((float4*)a_d)[node] = make_float4(rd[0], rd[1], rd[2], rd[3]);
}

__device__ __forceinline__ float edge_w(float v) {
    v = v > 0.f ? v : SLOPE * v;      // leaky relu
    return __expf(v);                 // no max-subtraction needed (|logit| < ~6)
}

// ---------------------------------------------------------------------------
// K4: softmax denominators  s[dst,h] += exp(leaky(a_s[src,h] + a_d[dst,h]))
// One thread per edge (incl. implicit self-loops at index >= E).
// ---------------------------------------------------------------------------
__global__ void logits_kernel(const int* __restrict__ ei, int E, int n,
                              const float* __restrict__ a_s,
                              const float* __restrict__ a_d,
                              float* __restrict__ s) {
    int e = blockIdx.x * blockDim.x + threadIdx.x;
    int Etot = E + n;
    if (e >= Etot) return;
    int src, dst;
    if (e < E) { src = ei[e]; dst = ei[E + e]; }
    else       { src = e - E; dst = src; }
    float4 a1 = ((const float4*)a_s)[src];
    float4 a2 = ((const float4*)a_d)[dst];
    float w0 = edge_w(a1.x + a2.x);
    float w1 = edge_w(a1.y + a2.y);
    float w2 = edge_w(a1.z + a2.z);
    float w3 = edge_w(a1.w + a2.w);
    float* sp = s + (size_t)dst * 4;
    atomicAdd(sp + 0, w0);
    atomicAdd(sp + 1, w1);
    atomicAdd(sp + 2, w2);
    atomicAdd(sp + 3, w3);
}

// ---------------------------------------------------------------------------
// K5: aggregation  out[dst,:] += alpha * h[src,:]
// 128 lanes per edge (2 waves), 2 edges per 256-thread block.
// ---------------------------------------------------------------------------
__global__ __launch_bounds__(256)
void aggregate_kernel(const int* __restrict__ ei, int E, int n,
                      const float* __restrict__ a_s,
                      const float* __restrict__ a_d,
                      const float* __restrict__ s,
                      const float* __restrict__ h,
                      float* __restrict__ out) {
    int lane = threadIdx.x & 127;
    int e = blockIdx.x * 2 + (threadIdx.x >> 7);
    int Etot = E + n;
    if (e >= Etot) return;
    int src, dst;
    if (e < E) { src = ei[e]; dst = ei[E + e]; }
    else       { src = e - E; dst = src; }
    int head = lane >> 5;
    float av = a_s[(size_t)src * 4 + head] + a_d[(size_t)dst * 4 + head];
    float coeff = edge_w(av) / s[(size_t)dst * 4 + head];
    float hv = h[(size_t)src * HC + lane];
    atomicAdd(out + (size_t)dst * HC + lane, coeff * hv);
}

// ---------------------------------------------------------------------------
extern "C" void kernel_launch(void* const* d_in, const int* in_sizes, int n_in,
                              void* d_out, int out_size, void* d_ws, size_t ws_size,
                              hipStream_t stream) {
    const float* x       = (const float*)d_in[0];
    const int*   ei      = (const int*)d_in[1];
    const float* W       = (const float*)d_in[2];
    const float* att_src = (const float*)d_in[3];
    const float* att_dst = (const float*)d_in[4];
    const float* bias    = (const float*)d_in[5];

    int n = in_sizes[0] / HC;        // 100000 (IN_DIM == HC == 128)
    int E = in_sizes[1] / 2;         // 1600000
    int Etot = E + n;

    // workspace layout (floats): h[n*128] | a_s[n*4] | a_d[n*4] | s[n*4]
    float* h   = (float*)d_ws;
    float* a_s = h   + (size_t)n * HC;
    float* a_d = a_s + (size_t)n * HEADS;
    float* s   = a_d + (size_t)n * HEADS;
    float* out = (float*)d_out;

    int total = n * HC;
    init_kernel<<<(total + 255) / 256, 256, 0, stream>>>(s, out, bias, n);
    gemm_kernel<<<(n + 127) / 128, 256, 0, stream>>>(x, W, h, n);
    att_kernel<<<(n + 255) / 256, 256, 0, stream>>>(h, att_src, att_dst, a_s, a_d, n);
    logits_kernel<<<(Etot + 255) / 256, 256, 0, stream>>>(ei, E, n, a_s, a_d, s);
    aggregate_kernel<<<(Etot + 1) / 2, 256, 0, stream>>>(ei, E, n, a_s, a_d, s, h, out);
}

// Round 2
// 491.192 us; speedup vs baseline: 2.5390x; 2.5390x over previous
//
#include <hip/hip_runtime.h>
#include <cstddef>

#define HEADS 4
#define HC 128          // HEADS * C
#define SLOPE 0.2f

// ---------------------------------------------------------------------------
// K2: h = x @ W   (N x 128) @ (128 x 128), fp32 vector GEMM
// ---------------------------------------------------------------------------
__global__ __launch_bounds__(256)
void gemm_kernel(const float* __restrict__ x, const float* __restrict__ W,
                 float* __restrict__ h, int n) {
    __shared__ float Wl[32 * 128];   // [kl][c]
    __shared__ float xT[32 * 132];   // [kl][r], padded stride 132

    const int tid  = threadIdx.x;
    const int row0 = blockIdx.x * 128;
    const int r0   = (tid >> 4) * 8;
    const int c0   = (tid & 15) * 8;

    float acc[8][8];
#pragma unroll
    for (int i = 0; i < 8; ++i)
#pragma unroll
        for (int j = 0; j < 8; ++j) acc[i][j] = 0.f;

    const float4* x4 = (const float4*)x;
    const float4* W4 = (const float4*)W;

    for (int kc = 0; kc < 4; ++kc) {
        for (int i = tid; i < 1024; i += 256)
            ((float4*)Wl)[i] = W4[kc * 1024 + i];
        for (int i = tid; i < 1024; i += 256) {
            int r = i >> 3;
            int q = i & 7;
            int grow = row0 + r;
            float4 v = make_float4(0.f, 0.f, 0.f, 0.f);
            if (grow < n) v = x4[(size_t)grow * 32 + kc * 8 + q];
            int kl = q * 4;
            xT[(kl + 0) * 132 + r] = v.x;
            xT[(kl + 1) * 132 + r] = v.y;
            xT[(kl + 2) * 132 + r] = v.z;
            xT[(kl + 3) * 132 + r] = v.w;
        }
        __syncthreads();
#pragma unroll
        for (int kl = 0; kl < 32; ++kl) {
            float4 xa = *(const float4*)&xT[kl * 132 + r0];
            float4 xb = *(const float4*)&xT[kl * 132 + r0 + 4];
            float4 wa = *(const float4*)&Wl[kl * 128 + c0];
            float4 wb = *(const float4*)&Wl[kl * 128 + c0 + 4];
            float xr[8] = {xa.x, xa.y, xa.z, xa.w, xb.x, xb.y, xb.z, xb.w};
            float wc[8] = {wa.x, wa.y, wa.z, wa.w, wb.x, wb.y, wb.z, wb.w};
#pragma unroll
            for (int i = 0; i < 8; ++i)
#pragma unroll
                for (int j = 0; j < 8; ++j)
                    acc[i][j] = fmaf(xr[i], wc[j], acc[i][j]);
        }
        __syncthreads();
    }

#pragma unroll
    for (int i = 0; i < 8; ++i) {
        int grow = row0 + r0 + i;
        if (grow < n) {
            float4 o0 = make_float4(acc[i][0], acc[i][1], acc[i][2], acc[i][3]);
            float4 o1 = make_float4(acc[i][4], acc[i][5], acc[i][6], acc[i][7]);
            *(float4*)&h[(size_t)grow * HC + c0]     = o0;
            *(float4*)&h[(size_t)grow * HC + c0 + 4] = o1;
        }
    }
}

// ---------------------------------------------------------------------------
// K3: per-node attention logit halves
// ---------------------------------------------------------------------------
__global__ void att_kernel(const float* __restrict__ h,
                           const float* __restrict__ att_src,
                           const float* __restrict__ att_dst,
                           float* __restrict__ a_s, float* __restrict__ a_d, int n) {
    int node = blockIdx.x * blockDim.x + threadIdx.x;
    if (node >= n) return;
    const float4* hv = (const float4*)(h + (size_t)node * HC);
    const float4* s4 = (const float4*)att_src;
    const float4* d4 = (const float4*)att_dst;
    float rs[4], rd[4];
#pragma unroll
    for (int hd = 0; hd < 4; ++hd) {
        float ss = 0.f, dd = 0.f;
#pragma unroll
        for (int q = 0; q < 8; ++q) {
            float4 hq = hv[hd * 8 + q];
            float4 a1 = s4[hd * 8 + q];
            float4 a2 = d4[hd * 8 + q];
            ss += hq.x * a1.x + hq.y * a1.y + hq.z * a1.z + hq.w * a1.w;
            dd += hq.x * a2.x + hq.y * a2.y + hq.z * a2.z + hq.w * a2.w;
        }
        rs[hd] = ss; rd[hd] = dd;
    }
    ((float4*)a_s)[node] = make_float4(rs[0], rs[1], rs[2], rs[3]);
    ((float4*)a_d)[node] = make_float4(rd[0], rd[1], rd[2], rd[3]);
}

__device__ __forceinline__ float edge_w(float v) {
    v = v > 0.f ? v : SLOPE * v;      // leaky relu
    return __expf(v);                 // |logit| small; no max-subtraction needed
}

// ---------------------------------------------------------------------------
// Counting-sort pipeline: deg histogram -> exclusive scan -> scatter
// ---------------------------------------------------------------------------
__global__ void zero_deg_kernel(int* __restrict__ deg, int n) {
    int i = blockIdx.x * blockDim.x + threadIdx.x;
    if (i < n) deg[i] = 0;
}

__global__ void hist_kernel(const int* __restrict__ ei, int E, int n,
                            int* __restrict__ deg) {
    int e = blockIdx.x * blockDim.x + threadIdx.x;
    if (e >= E + n) return;
    int dst = (e < E) ? ei[E + e] : (e - E);
    atomicAdd(&deg[dst], 1);
}

// per-1024-chunk exclusive scan; cursor[i] = exclusive start within chunk,
// bsum[b] = chunk total
__global__ __launch_bounds__(1024)
void scan1_kernel(const int* __restrict__ deg, int* __restrict__ cursor,
                  int* __restrict__ bsum, int n) {
    __shared__ int tmp[1024];
    int t = threadIdx.x;
    int i = blockIdx.x * 1024 + t;
    int d = (i < n) ? deg[i] : 0;
    tmp[t] = d;
    __syncthreads();
#pragma unroll
    for (int off = 1; off < 1024; off <<= 1) {
        int v = (t >= off) ? tmp[t - off] : 0;
        __syncthreads();
        tmp[t] += v;
        __syncthreads();
    }
    if (i < n) cursor[i] = tmp[t] - d;           // exclusive
    if (t == 1023) bsum[blockIdx.x] = tmp[t];    // chunk total
}

// exclusive scan of up to 128 chunk totals (NB = ceil(n/1024) <= 128)
__global__ __launch_bounds__(128)
void scan2_kernel(int* __restrict__ bsum, int nb) {
    __shared__ int tmp[128];
    int t = threadIdx.x;
    int d = (t < nb) ? bsum[t] : 0;
    tmp[t] = d;
    __syncthreads();
#pragma unroll
    for (int off = 1; off < 128; off <<= 1) {
        int v = (t >= off) ? tmp[t - off] : 0;
        __syncthreads();
        tmp[t] += v;
        __syncthreads();
    }
    if (t < nb) bsum[t] = tmp[t] - d;            // exclusive
}

__global__ void scan3_kernel(int* __restrict__ cursor,
                             const int* __restrict__ bsum, int n) {
    int i = blockIdx.x * blockDim.x + threadIdx.x;
    if (i < n) cursor[i] += bsum[i >> 10];
}

// scatter: sorted[pos] = src, grouping edges by dst.
// After this, cursor[i] == global inclusive end of row i.
__global__ void scatter_kernel(const int* __restrict__ ei, int E, int n,
                               int* __restrict__ cursor, int* __restrict__ sorted) {
    int e = blockIdx.x * blockDim.x + threadIdx.x;
    if (e >= E + n) return;
    int src, dst;
    if (e < E) { src = ei[e]; dst = ei[E + e]; }
    else       { src = e - E; dst = src; }
    int pos = atomicAdd(&cursor[dst], 1);
    sorted[pos] = src;
}

// ---------------------------------------------------------------------------
// K5: fused softmax + aggregation, atomic-free.
// One 128-thread block per dst node; lane owns one output channel.
// out[dst,:] = (sum_e w_e * h[src_e,:]) / (sum_e w_e) + bias
// ---------------------------------------------------------------------------
__global__ __launch_bounds__(128)
void aggregate_kernel(const int* __restrict__ cursor,
                      const int* __restrict__ sorted,
                      const float* __restrict__ a_s,
                      const float* __restrict__ a_d,
                      const float* __restrict__ h,
                      const float* __restrict__ bias,
                      float* __restrict__ out, int n) {
    int dst  = blockIdx.x;
    int lane = threadIdx.x;
    int head = lane >> 5;
    int start = (dst == 0) ? 0 : cursor[dst - 1];
    int end   = cursor[dst];

    float ad = a_d[(size_t)dst * 4 + head];
    float acc = 0.f, wsum = 0.f;

    int j = start;
    for (; j + 3 < end; j += 4) {
        int s0 = sorted[j], s1 = sorted[j + 1], s2 = sorted[j + 2], s3 = sorted[j + 3];
        float w0 = edge_w(a_s[(size_t)s0 * 4 + head] + ad);
        float w1 = edge_w(a_s[(size_t)s1 * 4 + head] + ad);
        float w2 = edge_w(a_s[(size_t)s2 * 4 + head] + ad);
        float w3 = edge_w(a_s[(size_t)s3 * 4 + head] + ad);
        float h0 = h[(size_t)s0 * HC + lane];
        float h1 = h[(size_t)s1 * HC + lane];
        float h2 = h[(size_t)s2 * HC + lane];
        float h3 = h[(size_t)s3 * HC + lane];
        acc  = fmaf(w0, h0, acc);  acc = fmaf(w1, h1, acc);
        acc  = fmaf(w2, h2, acc);  acc = fmaf(w3, h3, acc);
        wsum += (w0 + w1) + (w2 + w3);
    }
    for (; j < end; ++j) {
        int s0 = sorted[j];
        float w0 = edge_w(a_s[(size_t)s0 * 4 + head] + ad);
        acc  = fmaf(w0, h[(size_t)s0 * HC + lane], acc);
        wsum += w0;
    }

    out[(size_t)dst * HC + lane] = acc / wsum + bias[lane];
}

// ---------------------------------------------------------------------------
extern "C" void kernel_launch(void* const* d_in, const int* in_sizes, int n_in,
                              void* d_out, int out_size, void* d_ws, size_t ws_size,
                              hipStream_t stream) {
    const float* x       = (const float*)d_in[0];
    const int*   ei      = (const int*)d_in[1];
    const float* W       = (const float*)d_in[2];
    const float* att_src = (const float*)d_in[3];
    const float* att_dst = (const float*)d_in[4];
    const float* bias    = (const float*)d_in[5];

    int n = in_sizes[0] / HC;        // 100000
    int E = in_sizes[1] / 2;         // 1600000
    int Etot = E + n;
    int NB = (n + 1023) / 1024;      // scan chunks (<=128)

    // workspace layout:
    // h [n*128 f] | a_s [n*4 f] | a_d [n*4 f] | deg [n i] | cursor [n i] |
    // bsum [128 i] | sorted [Etot i]
    float* h      = (float*)d_ws;
    float* a_s    = h   + (size_t)n * HC;
    float* a_d    = a_s + (size_t)n * HEADS;
    int*   deg    = (int*)(a_d + (size_t)n * HEADS);
    int*   cursor = deg + n;
    int*   bsum   = cursor + n;
    int*   sorted = bsum + 128;
    float* out    = (float*)d_out;

    gemm_kernel<<<(n + 127) / 128, 256, 0, stream>>>(x, W, h, n);
    att_kernel<<<(n + 255) / 256, 256, 0, stream>>>(h, att_src, att_dst, a_s, a_d, n);

    zero_deg_kernel<<<(n + 255) / 256, 256, 0, stream>>>(deg, n);
    hist_kernel<<<(Etot + 255) / 256, 256, 0, stream>>>(ei, E, n, deg);
    scan1_kernel<<<NB, 1024, 0, stream>>>(deg, cursor, bsum, n);
    scan2_kernel<<<1, 128, 0, stream>>>(bsum, NB);
    scan3_kernel<<<(n + 255) / 256, 256, 0, stream>>>(cursor, bsum, n);
    scatter_kernel<<<(Etot + 255) / 256, 256, 0, stream>>>(ei, E, n, cursor, sorted);

    aggregate_kernel<<<n, 128, 0, stream>>>(cursor, sorted, a_s, a_d, h, bias, out, n);
}